// Round 14
// baseline (57.372 us; speedup 1.0000x reference)
//
#include <hip/hip_runtime.h>
#include <hip/hip_bf16.h>

// SPP patch extraction, fused single-launch.
// feat (512,48,48) fp32; scales {4,6,8,10,12,14,16}, stride-2 SxS windows,
// adaptive max pool 7x7 -> (ny*nx, 512*49) per scale, concatenated.
//
// R14 = R10 structure with CH=16 (16 channels per block):
//  - contiguous write run per (patch, block) = 784 floats = 3136 B = exactly
//    49 cache lines, line-aligned (CH=8's 1568 B = 24.5 lines meant every
//    other run started mid-line and shared lines across blocks).
//  - halves the number of interleaved write streams per patch region.
//  Fills prove ~3 waves/CU saturate the store path, so 4 blocks/CU (16
//  waves) from the larger LDS (35 KB) is ample.
// Phases: P2 y-binned rp (float2 reads, one barrier); wave-autonomous emit:
// P3 x-pool (two 56-lane halves, compile-time bins) -> owb slice; P4 196
// float4 dwordx4 stores. DS wave-ordered -> fences only, no barriers.

#define HW 48
#define CSTR (HW * HW)   // 2304
#define POOL 7
#define PE 25088         // 512*49 elems per patch
#define CH 16            // channels per block
#define NROW (CH * POOL) // 112 rp rows
#define RPS 50           // rp row stride (floats)

constexpr int cdiv7(int x) { return (x + 6) / 7; }
constexpr int nyf(int S) { return (HW - S) / 2 + 1; }
constexpr int max_bin(int S) {
    int m = 0;
    for (int i = 0; i < POOL; ++i) {
        int a = (i * S) / POOL, b = cdiv7((i + 1) * S);
        if (b - a > m) m = b - a;
    }
    return m;
}

template <int S>
__device__ __forceinline__ void run_scale(int b, const float* __restrict__ feat,
                                          float* __restrict__ outp,
                                          float* rp, float* owb) {
    constexpr int NX = nyf(S);
    constexpr int MB = max_bin(S);
    const int tid = threadIdx.x;
    const int iy = b >> 5;           // 32 chunks of 16 channels
    const int c0 = (b & 31) * CH;
    const int y0 = iy * 2;

    // ---- P2: rp[row=c*7+py][x] = y-binned max, float2, direct from cache ----
    const float* fb = feat + (size_t)c0 * CSTR + y0 * HW;
    for (int t = tid; t < CH * POOL * (HW / 2); t += 256) {   // 2688
        int c = t / (POOL * 24);
        int rem = t - c * (POOL * 24);
        int py = rem / 24;
        int xl = rem - py * 24;                               // x = 2*xl
        int ay = (py * S) / POOL;
        int szy = cdiv7((py + 1) * S) - ay;
        const float* wb = fb + c * CSTR + ay * HW + 2 * xl;
        float2 m = *(const float2*)wb;
#pragma unroll
        for (int r = 1; r < MB; ++r) {
            float2 v = *(const float2*)(wb + min(r, szy - 1) * HW);
            m.x = fmaxf(m.x, v.x);
            m.y = fmaxf(m.y, v.y);
        }
        *(float2*)(rp + (c * POOL + py) * RPS + 2 * xl) = m;
    }
    __syncthreads();                 // the only barrier

    // ---- wave-autonomous emit ----
    const int wv = tid >> 6;
    const int lane = tid & 63;
    float* myout = owb + wv * (NROW * 7);   // 784 floats per wave
    float* obase = outp + (size_t)iy * NX * PE + (size_t)c0 * 49;

    for (int ix = wv; ix < NX; ix += 4) {
        // P3: rows 0..111 in two 56-lane halves; bin indices compile-time
        if (lane < 56) {
#pragma unroll
            for (int h = 0; h < 2; ++h) {
                int row = h * 56 + lane;
                const float* v = rp + row * RPS + 2 * ix;   // 8B-aligned
                float x[S];
#pragma unroll
                for (int k = 0; k < S / 2; ++k) {
                    float2 p = *(const float2*)(v + 2 * k);
                    x[2 * k] = p.x;
                    x[2 * k + 1] = p.y;
                }
                float* ob = myout + row * 7;                // output order
#pragma unroll
                for (int px = 0; px < POOL; ++px) {
                    int ax = (px * S) / POOL;               // compile-time
                    int bx = cdiv7((px + 1) * S);
                    float m = x[ax];
#pragma unroll
                    for (int k = ax + 1; k < bx; ++k) m = fmaxf(m, x[k]);
                    ob[px] = m;
                }
            }
        }
        asm volatile("" ::: "memory");  // keep P3 writes before P4 reads
        // P4: 196 float4 -> dense coalesced dwordx4 stores (49 full lines)
        float* od = obase + (size_t)ix * PE;
#pragma unroll
        for (int i = 0; i < 4; ++i) {
            int k = lane + 64 * i;
            if (k < 196) {
                float4 vv = *(const float4*)(myout + 4 * k);
                *(float4*)(od + 4 * k) = vv;
            }
        }
        asm volatile("" ::: "memory");  // keep P4 reads before next P3 writes
    }
}

__global__ __launch_bounds__(256) void spp_fused(const float* __restrict__ feat,
                                                 float* __restrict__ out) {
    __shared__ float rp[NROW * RPS];               // 22.4 KB
    __shared__ __align__(16) float owb[4 * NROW * 7]; // 12.5 KB
    int b = blockIdx.x;
    // Heavy-first: S=16,14,12,10,8,6,4 (32 chunks x ny blocks each).
    if (b < 544)       run_scale<16>(b,        feat, out + (size_t)2539 * PE, rp, owb);
    else if (b < 1120) run_scale<14>(b - 544,  feat, out + (size_t)2215 * PE, rp, owb);
    else if (b < 1728) run_scale<12>(b - 1120, feat, out + (size_t)1854 * PE, rp, owb);
    else if (b < 2368) run_scale<10>(b - 1728, feat, out + (size_t)1454 * PE, rp, owb);
    else if (b < 3040) run_scale<8>(b - 2368,  feat, out + (size_t)1013 * PE, rp, owb);
    else if (b < 3744) run_scale<6>(b - 3040,  feat, out + (size_t)529  * PE, rp, owb);
    else               run_scale<4>(b - 3744,  feat, out,                     rp, owb);
}

extern "C" void kernel_launch(void* const* d_in, const int* in_sizes, int n_in,
                              void* d_out, int out_size, void* d_ws, size_t ws_size,
                              hipStream_t stream) {
    const float* feat = (const float*)d_in[0];
    float* out = (float*)d_out;
    spp_fused<<<4480, 256, 0, stream>>>(feat, out);
}